// Round 8
// baseline (385.428 us; speedup 1.0000x reference)
//
#include <hip/hip_runtime.h>
#include <math.h>

#define B_ 2
#define N_ 16384
#define D_ 512
#define C_ 4
#define K_ 8
#define ROWS (B_*N_)      // 32768 rows per side
#define ROWS2 (2*ROWS)    // 65536 rows both sides
#define EPS_ 1e-12f

typedef unsigned short u16;
typedef unsigned int u32;
using short8  = __attribute__((ext_vector_type(8))) short;
using float4v = __attribute__((ext_vector_type(4))) float;

__device__ __forceinline__ u16 f2bf(float f) {
    union { float f; u32 u; } v; v.f = f;
    u32 r = v.u + 0x7fffu + ((v.u >> 16) & 1u);
    return (u16)(r >> 16);
}
__device__ __forceinline__ u32 pack2(float a, float b) {
    return (u32)f2bf(a) | ((u32)f2bf(b) << 16);
}
__device__ __forceinline__ float bf2f(u16 h) {
    union { u32 u; float f; } v; v.u = ((u32)h) << 16;
    return v.f;
}
__device__ __forceinline__ float fsigmoid(float x) { return 1.0f / (1.0f + __expf(-x)); }
__device__ __forceinline__ float ftanh(float x)    { return 1.0f - 2.0f / (__expf(2.0f * x) + 1.0f); }

__device__ __forceinline__ void load_lds16(const u16* g, u16* l) {
    __builtin_amdgcn_global_load_lds(
        (const __attribute__((address_space(1))) u32*)g,
        (__attribute__((address_space(3))) u32*)l, 16, 0, 0);
}
// Stage 8 rows x 64 k (bf16) of a row-major tile (row stride 512 u16) into LDS,
// fully coalesced, XOR-swizzled. LDS addr(r,c)=r*64 + (c^(r&7))*8 (u16).
__device__ __forceinline__ void stage_rows8(const u16* gtile, u16* ldsTile, int g, int lane) {
    int rg = lane >> 3;
    int c  = (lane & 7) ^ rg;
    load_lds16(gtile + (size_t)(g * 8 + rg) * 512 + c * 8, ldsTile + g * 512);
}
#define AFRAG(lds, R, c) (*(const short8*)&(lds)[(R) * 64 + (((c) ^ ((R) & 7)) * 8)])
// Fragment-packed B: frag(nf, ks)[lane][e] = Bt[nf*16 + (lane&15)][ks*32 + (lane>>4)*8 + e]
#define BFRAG(Bf, nf, ks, lane) (*(const short8*)&(Bf)[((size_t)((nf) * 16 + (ks)) << 9) + ((lane) << 3)])

// ---------------- P0: weight prep (fragment-major packing) ----------------
__global__ __launch_bounds__(256) void prep_weights_kernel(
    const float* __restrict__ Wp, const float* __restrict__ Wv, const float* __restrict__ Wu,
    const float* __restrict__ bv, const float* __restrict__ bu, const float* __restrict__ desc,
    u16* __restrict__ WpF, u16* __restrict__ WvuF, float* __restrict__ bvu,
    u16* __restrict__ descF)
{
    int idx = blockIdx.x * 256 + threadIdx.x;   // 0 .. 262143
    // fragment decode: idx = ((nf*16 + ks)*64 + l)*8 + e
    int e = idx & 7, l = (idx >> 3) & 63, ks = (idx >> 9) & 15, nf = idx >> 13;
    int k = ks * 32 + ((l >> 4) << 3) + e;
    int n = (nf << 4) + (l & 15);
    WpF[idx] = f2bf(Wp[(size_t)k * 512 + n]);
    int half = nf & 1, h = (nf >> 1) * 16 + (l & 15);
    WvuF[idx] = f2bf(half ? Wu[(size_t)k * 256 + h] : Wv[(size_t)k * 256 + h]);
    if (idx < 512) {
        int tl = idx >> 4, pr = tl >> 1, hf = tl & 1, hh = pr * 16 + (idx & 15);
        bvu[idx] = hf ? bu[hh] : bv[hh];
    }
    if (idx < 16384) {
        int j = idx & 7, dl = (idx >> 3) & 63, g = (idx >> 9) & 1, kt = idx >> 10;
        descF[idx] = f2bf(desc[(size_t)(g * 16 + (dl & 15)) * 512 + kt * 32 + (dl >> 4) * 8 + j]);
    }
}

// ---------------- K0: per-row L2-normalize x and cast to bf16 (both sides) ---------
__global__ __launch_bounds__(256) void rownorm_cast_kernel(
    const float* __restrict__ x_s, const float* __restrict__ x_l, u16* __restrict__ xn)
{
    int wave = threadIdx.x >> 6, lane = threadIdx.x & 63;
    size_t row = (size_t)blockIdx.x * 4 + wave;
    const float* xr = (row < (size_t)ROWS) ? (x_s + row * D_)
                                           : (x_l + (row - ROWS) * D_);
    float4 a = *(const float4*)&xr[lane * 8];
    float4 b = *(const float4*)&xr[lane * 8 + 4];
    float s = a.x*a.x + a.y*a.y + a.z*a.z + a.w*a.w
            + b.x*b.x + b.y*b.y + b.z*b.z + b.w*b.w;
#pragma unroll
    for (int off = 32; off; off >>= 1) s += __shfl_xor(s, off, 64);
    float inv = 1.0f / fmaxf(sqrtf(s), EPS_);
    uint4 o;
    o.x = pack2(a.x * inv, a.y * inv);
    o.y = pack2(a.z * inv, a.w * inv);
    o.z = pack2(b.x * inv, b.y * inv);
    o.w = pack2(b.z * inv, b.w * inv);
    *(uint4*)&xn[row * D_ + lane * 8] = o;
}

// ---------------- K1: FUSED proj-GEMM -> LDS tile -> gate-GEMM + cls + Gram -------
// Loop 1 stages xn chunk tt directly into (otherwise unused) tile chunk tt:
// 8 distinct chunks -> no WAR hazard; 2-chunk prefetch; counted vmcnt + raw barrier.
__global__ __launch_bounds__(512, 2) void fused_kernel(
    const u16* __restrict__ A,          // xn
    const u16* __restrict__ BpF,        // W_proj frag-packed
    const u16* __restrict__ BvuF,       // Wv/Wu frag-packed interleaved
    const u16* __restrict__ descF,
    const float* __restrict__ bias,     // b_proj
    const float* __restrict__ bvu, const float* __restrict__ w_attn,
    u16* __restrict__ Cp,               // xpraw out (global, for pool)
    float* __restrict__ invn, float* __restrict__ Araw,
    float* __restrict__ out10)
{
    __shared__ u16 tile[65536];         // 128 KB: xn chunks during loop 1, xpraw tile after
    __shared__ float sInvF[128];
    __shared__ float redA[512];
    int t = threadIdx.x, wave = t >> 6, lane = t & 63;
    int lr = lane & 15, lq = lane >> 4;
    int wm = wave >> 2, wn = wave & 3;  // wave covers rows wm*64..+64, cols wn*128..+128
    int M0 = blockIdx.x * 128;
    const u16* Arow = A + (size_t)M0 * 512;

    // ================= loop 1: xpraw = xn @ Wp + b =================
    float4v acc1[4][8];
#pragma unroll
    for (int i = 0; i < 4; ++i)
#pragma unroll
        for (int j = 0; j < 8; ++j)
#pragma unroll
            for (int r = 0; r < 4; ++r) acc1[i][j][r] = 0.f;

#define STAGE1(c) { stage_rows8(Arow + (c) * 64, tile + (size_t)(c) * 8192, wave * 2 + 0, lane); \
                    stage_rows8(Arow + (c) * 64, tile + (size_t)(c) * 8192, wave * 2 + 1, lane); }
#define GCOMP1(TCH, BR) \
    { _Pragma("unroll") \
      for (int kt = 0; kt < 2; ++kt) { \
          short8 af[4]; \
          _Pragma("unroll") \
          for (int i_ = 0; i_ < 4; ++i_) \
              af[i_] = AFRAG(TCH, wm * 64 + i_ * 16 + lr, kt * 4 + lq); \
          _Pragma("unroll") \
          for (int i_ = 0; i_ < 4; ++i_) \
              _Pragma("unroll") \
              for (int j_ = 0; j_ < 8; ++j_) \
                  acc1[i_][j_] = __builtin_amdgcn_mfma_f32_16x16x32_bf16(BR[kt * 8 + j_], af[i_], acc1[i_][j_], 0, 0, 0); \
      } }
#define LOADB1(BR, ttv) \
    { _Pragma("unroll") \
      for (int j_ = 0; j_ < 8; ++j_) { \
          BR[j_]     = BFRAG(BpF, wn * 8 + j_, (ttv) * 2 + 0, lane); \
          BR[8 + j_] = BFRAG(BpF, wn * 8 + j_, (ttv) * 2 + 1, lane); \
      } }

    STAGE1(0); STAGE1(1);
    asm volatile("s_waitcnt vmcnt(2)" ::: "memory");
    __builtin_amdgcn_s_barrier();

#pragma unroll 1
    for (int tt = 0; tt < 6; ++tt) {
        short8 bfr[16];
        LOADB1(bfr, tt);
        asm volatile("" ::: "memory");     // pin: B loads issue BEFORE next stage
        STAGE1(tt + 2);
        const u16* tch = tile + (size_t)tt * 8192;
        GCOMP1(tch, bfr);
        asm volatile("s_waitcnt vmcnt(2)" ::: "memory");   // chunk tt+1 drained; tt+2 in flight
        __builtin_amdgcn_s_barrier();
    }
    {   // tt = 6
        short8 bfr[16];
        LOADB1(bfr, 6);
        const u16* tch = tile + (size_t)6 * 8192;
        GCOMP1(tch, bfr);
        asm volatile("s_waitcnt vmcnt(0)" ::: "memory");   // chunk 7 ready
        __builtin_amdgcn_s_barrier();
    }
    {   // tt = 7
        short8 bfr[16];
        LOADB1(bfr, 7);
        const u16* tch = tile + (size_t)7 * 8192;
        GCOMP1(tch, bfr);
    }
    __syncthreads();   // all waves done reading xn chunks before epilogue overwrites tile

    // ---- epilogue 1: +bias, bf16-round, write global xpraw AND the LDS tile ----
    {
        float4 b4[8];
#pragma unroll
        for (int j = 0; j < 8; ++j)
            b4[j] = *(const float4*)&bias[wn * 128 + j * 16 + lq * 4];
#pragma unroll
        for (int i = 0; i < 4; ++i) {
            int row = wm * 64 + i * 16 + lr;
            u16* crow = Cp + (size_t)(M0 + row) * 512;
#pragma unroll
            for (int j = 0; j < 8; ++j) {
                int col = wn * 128 + j * 16 + lq * 4;
                u16 h0 = f2bf(acc1[i][j][0] + b4[j].x);
                u16 h1 = f2bf(acc1[i][j][1] + b4[j].y);
                u16 h2 = f2bf(acc1[i][j][2] + b4[j].z);
                u16 h3 = f2bf(acc1[i][j][3] + b4[j].w);
                uint2 o;
                o.x = (u32)h0 | ((u32)h1 << 16);
                o.y = (u32)h2 | ((u32)h3 << 16);
                *(uint2*)&crow[col] = o;
                // LDS tile write in the SAME swizzled layout AFRAG expects:
                int kc = col >> 6, cc = col & 63;
                int c8 = cc >> 3, off8 = cc & 7;   // off8 in {0,4}
                *(uint2*)&tile[kc * 8192 + row * 64 + ((c8 ^ (row & 7)) * 8) + off8] = o;
            }
        }
    }
    __syncthreads();   // tile fully visible; loop 2 below is barrier-free

    // ================= loop 2: gate GEMM + cls + Gram, A from LDS =================
    float4v acc2[4][8];
    float4v accS[2], accG;
#pragma unroll
    for (int i = 0; i < 4; ++i)
#pragma unroll
        for (int j = 0; j < 8; ++j)
#pragma unroll
            for (int r = 0; r < 4; ++r) acc2[i][j][r] = 0.f;
#pragma unroll
    for (int r = 0; r < 4; ++r) { accS[0][r] = 0.f; accS[1][r] = 0.f; accG[r] = 0.f; }

#pragma unroll 2
    for (int tt = 0; tt < 8; ++tt) {
        const u16* tch = tile + (size_t)tt * 8192;
#pragma unroll
        for (int kt = 0; kt < 2; ++kt) {
            int ks = tt * 2 + kt;
            // cls + Gram on this wave's 16 rows
            short8 afc = AFRAG(tch, wave * 16 + lr, kt * 4 + lq);
            short8 d0 = *(const short8*)&descF[((ks * 2 + 0) << 9) + (lane << 3)];
            short8 d1 = *(const short8*)&descF[((ks * 2 + 1) << 9) + (lane << 3)];
            accS[0] = __builtin_amdgcn_mfma_f32_16x16x32_bf16(afc, d0, accS[0], 0, 0, 0);
            accS[1] = __builtin_amdgcn_mfma_f32_16x16x32_bf16(afc, d1, accS[1], 0, 0, 0);
            accG    = __builtin_amdgcn_mfma_f32_16x16x32_bf16(afc, afc, accG, 0, 0, 0);
            // main gate GEMM
            short8 af[4], bfr[8];
#pragma unroll
            for (int i = 0; i < 4; ++i)
                af[i] = AFRAG(tch, wm * 64 + i * 16 + lr, kt * 4 + lq);
#pragma unroll
            for (int j = 0; j < 8; ++j)
                bfr[j] = BFRAG(BvuF, wn * 8 + j, ks, lane);
#pragma unroll
            for (int i = 0; i < 4; ++i)
#pragma unroll
                for (int j = 0; j < 8; ++j)
                    acc2[i][j] = __builtin_amdgcn_mfma_f32_16x16x32_bf16(bfr[j], af[i], acc2[i][j], 0, 0, 0);
        }
    }

    // ---- invn from Gram diagonal (each wave owns rows wave*16..+16) ----
#pragma unroll
    for (int r = 0; r < 4; ++r) {
        if (lr == lq * 4 + r) {
            float iv = 1.0f / fmaxf(sqrtf(accG[r]), EPS_);
            sInvF[wave * 16 + lq * 4 + r] = iv;
            invn[M0 + wave * 16 + lq * 4 + r] = iv;
        }
    }
    __syncthreads();

    // ---- class scores ----
    {
        const float scale = 0.04419417382415922f;   // 512^-0.5
        int side = (M0 >= ROWS) ? 1 : 0;
        float* cls = out10 + (size_t)side * ((size_t)ROWS * 4);
        int rbase = M0 - side * ROWS + wave * 16;
#pragma unroll
        for (int r = 0; r < 4; ++r) {
            int rloc = rbase + lq * 4 + r;
            float iv = sInvF[wave * 16 + lq * 4 + r];
            float sv0 = accS[0][r] * iv, sv1 = accS[1][r] * iv;
#pragma unroll
            for (int g = 0; g < 2; ++g) {
                float s = g ? sv1 : sv0;
                float ts = s * scale;
                float mx = ts;
                mx = fmaxf(mx, __shfl_xor(mx, 1, 64));
                mx = fmaxf(mx, __shfl_xor(mx, 2, 64));
                mx = fmaxf(mx, __shfl_xor(mx, 4, 64));
                float e = __expf(ts - mx);
                float num = e * s, den = e;
                num += __shfl_xor(num, 1, 64); den += __shfl_xor(den, 1, 64);
                num += __shfl_xor(num, 2, 64); den += __shfl_xor(den, 2, 64);
                num += __shfl_xor(num, 4, 64); den += __shfl_xor(den, 4, 64);
                if ((lr & 7) == 0) {
                    int c = g * 2 + ((lr >> 3) & 1);
                    cls[(size_t)rloc * 4 + c] = num / den;
                }
            }
        }
    }

    // ---- gated-attention scalar: full row in block -> single Araw ----
    {
        int colbase = wn * 128;
        int hbase = wn * 64;
        float4 bv4[4], bu4[4], w4[4];
#pragma unroll
        for (int p = 0; p < 4; ++p) {
            int nv = colbase + p * 32 + lq * 4;
            bv4[p] = *(const float4*)&bvu[nv];
            bu4[p] = *(const float4*)&bvu[nv + 16];
            w4[p]  = *(const float4*)&w_attn[hbase + p * 16 + lq * 4];
        }
#pragma unroll
        for (int i = 0; i < 4; ++i) {
            int rloc = wm * 64 + i * 16 + lr;
            float iv = sInvF[rloc];
            float part = 0.f;
#pragma unroll
            for (int p = 0; p < 4; ++p) {
#pragma unroll
                for (int r = 0; r < 4; ++r) {
                    float v = acc2[i][2 * p][r] * iv + (&bv4[p].x)[r];
                    float u = acc2[i][2 * p + 1][r] * iv + (&bu4[p].x)[r];
                    part += ftanh(v) * (&w4[p].x)[r] * fsigmoid(u);
                }
            }
            part += __shfl_xor(part, 16, 64);
            part += __shfl_xor(part, 32, 64);
            if (lq == 0) redA[wn * 128 + rloc] = part;
        }
    }
    __syncthreads();
    if (t < 128)
        Araw[M0 + t] = redA[t] + redA[128 + t] + redA[256 + t] + redA[384 + t];
}

// ---------------- K5: per-group softmax stats (max, 1/expsum) in one kernel -------
// grid (4): one block per (side,batch) group of 16384 rows.
__global__ __launch_bounds__(256) void asoftmax_kernel(
    const float* __restrict__ Araw, float* __restrict__ mg)
{
    __shared__ float red[256];
    int t = threadIdx.x, g = blockIdx.x;
    const float4* a4 = (const float4*)(Araw + (size_t)g * N_);
    float m = -1e30f;
    for (int i = t; i < N_ / 4; i += 256) {
        float4 v = a4[i];
        m = fmaxf(m, fmaxf(fmaxf(v.x, v.y), fmaxf(v.z, v.w)));
    }
    red[t] = m; __syncthreads();
    for (int s = 128; s; s >>= 1) { if (t < s) red[t] = fmaxf(red[t], red[t + s]); __syncthreads(); }
    m = red[0]; __syncthreads();
    float e = 0.f;
    for (int i = t; i < N_ / 4; i += 256) {
        float4 v = a4[i];
        e += __expf(v.x - m) + __expf(v.y - m) + __expf(v.z - m) + __expf(v.w - m);
    }
    red[t] = e; __syncthreads();
    for (int s = 128; s; s >>= 1) { if (t < s) red[t] += red[t + s]; __syncthreads(); }
    if (t == 0) {
        mg[g * 2] = m;
        mg[g * 2 + 1] = 1.0f / red[0];
    }
}

// ---------------- K6: pooling with inline softmax normalize ----------------
__global__ __launch_bounds__(256) void pool_kernel(
    const float* __restrict__ Araw, const float* __restrict__ invn,
    const float* __restrict__ mg, const u16* __restrict__ xpraw,
    float* __restrict__ slideAll)
{
    __shared__ float lds[4][512];
    int t = threadIdx.x, wave = t >> 6, lane = t & 63;
    int g = blockIdx.y;
    float m = mg[g * 2], is = mg[g * 2 + 1];
    size_t row0 = (size_t)g * N_ + (size_t)blockIdx.x * 256 + wave;
    float a[8] = {};
    for (int r = 0; r < 64; ++r) {
        size_t row = row0 + r * 4;
        float av = __expf(Araw[row] - m) * is * invn[row];
        uint4 pk = *(const uint4*)&xpraw[row * D_ + lane * 8];
        a[0] += av * bf2f((u16)pk.x); a[1] += av * bf2f((u16)(pk.x >> 16));
        a[2] += av * bf2f((u16)pk.y); a[3] += av * bf2f((u16)(pk.y >> 16));
        a[4] += av * bf2f((u16)pk.z); a[5] += av * bf2f((u16)(pk.z >> 16));
        a[6] += av * bf2f((u16)pk.w); a[7] += av * bf2f((u16)(pk.w >> 16));
    }
#pragma unroll
    for (int i = 0; i < 8; ++i) lds[wave][lane * 8 + i] = a[i];
    __syncthreads();
#pragma unroll
    for (int q = 0; q < 2; ++q) {
        int c = t * 2 + q;
        float s = lds[0][c] + lds[1][c] + lds[2][c] + lds[3][c];
        atomicAdd(&slideAll[(size_t)g * 512 + c], s);
    }
}

// ---------------- K7: finalize ----------------
__global__ __launch_bounds__(512) void finalize_kernel(
    const float* __restrict__ slide_s, const float* __restrict__ slide_l,
    const float* __restrict__ desc, float* __restrict__ out)
{
    __shared__ float txt[4][512];
    __shared__ float ssn[2][512];
    __shared__ float sln[2][512];
    __shared__ float red[512];
    __shared__ float lg[8];
    int t = threadIdx.x;

    auto reduceSum = [&](float v) -> float {
        red[t] = v; __syncthreads();
        for (int s = 256; s; s >>= 1) { if (t < s) red[t] += red[t + s]; __syncthreads(); }
        float r = red[0]; __syncthreads();
        return r;
    };

    for (int c = 0; c < 4; ++c) {
        float m = -1e30f;
        for (int k = 0; k < 8; ++k) m = fmaxf(m, desc[((size_t)c * 8 + k) * 512 + t]);
        float ss = reduceSum(m * m);
        txt[c][t] = m / fmaxf(sqrtf(ss), EPS_);
    }
    for (int b = 0; b < 2; ++b) {
        float v = slide_s[b * 512 + t];
        float ss = reduceSum(v * v);
        ssn[b][t] = v / fmaxf(sqrtf(ss), EPS_);
        v = slide_l[b * 512 + t];
        ss = reduceSum(v * v);
        sln[b][t] = v / fmaxf(sqrtf(ss), EPS_);
    }
    __syncthreads();
    for (int b = 0; b < 2; ++b)
        for (int c = 0; c < 4; ++c) {
            float v = ssn[b][t] * txt[c][t] + sln[b][t] * txt[c][t];
            float s = reduceSum(v);
            if (t == 0) lg[b * 4 + c] = s;
        }
    __syncthreads();
    if (t < 2) {
        int b = t;
        float m = -1e30f;
        for (int c = 0; c < 4; ++c) m = fmaxf(m, lg[b * 4 + c]);
        float e[4]; float den = 0.f;
        for (int c = 0; c < 4; ++c) { e[c] = expf(lg[b * 4 + c] - m); den += e[c]; }
        int am = 0; float bm = -1.f;
        for (int c = 0; c < 4; ++c) {
            float pcl = e[c] / den;
            out[b * 4 + c] = pcl;
            if (pcl > bm) { bm = pcl; am = c; }
        }
        out[8 + b] = (float)am;
    }
}

extern "C" void kernel_launch(void* const* d_in, const int* in_sizes, int n_in,
                              void* d_out, int out_size, void* d_ws, size_t ws_size,
                              hipStream_t stream) {
    const float* x_s    = (const float*)d_in[0];
    const float* x_l    = (const float*)d_in[2];
    const float* W_proj = (const float*)d_in[4];
    const float* b_proj = (const float*)d_in[5];
    const float* desc   = (const float*)d_in[6];
    const float* Wv     = (const float*)d_in[7];
    const float* bv     = (const float*)d_in[8];
    const float* Wu     = (const float*)d_in[9];
    const float* bu     = (const float*)d_in[10];
    const float* w_attn = (const float*)d_in[11];
    float* out = (float*)d_out;

    // workspace layout (bytes):
    //  0         : xn    bf16 [65536x512]  (67108864)
    //  67108864  : xpraw bf16 [65536x512]  (67108864)
    //  134217728 : WpF   bf16 frag-packed  (524288)
    //  134742016 : WvuF  bf16 frag-packed  (524288)
    //  135266304 : descF bf16 fragment     (32768)
    //  135299072 : bvu   f32 [512]         (2048)
    //  135301120 : invn  f32 [65536]       (262144)
    //  135563264 : Araw  f32 [65536]       (262144)
    //  135825408 : mg    f32 [4x2]         (1024 pad)
    //  135826432 : slideAll f32 [4x512]    (8192)
    char* w = (char*)d_ws;
    u16* xn        = (u16*)w;
    u16* xpraw     = (u16*)(w + 67108864);
    u16* WpF       = (u16*)(w + 134217728);
    u16* WvuF      = (u16*)(w + 134742016);
    u16* descF     = (u16*)(w + 135266304);
    float* bvu     = (float*)(w + 135299072);
    float* invn    = (float*)(w + 135301120);
    float* Araw    = (float*)(w + 135563264);
    float* mg      = (float*)(w + 135825408);
    float* slideAll= (float*)(w + 135826432);

    hipMemsetAsync(slideAll, 0, 8192, stream);
    prep_weights_kernel<<<1024, 256, 0, stream>>>(W_proj, Wv, Wu, bv, bu, desc,
                                                  WpF, WvuF, bvu, descF);

    rownorm_cast_kernel<<<ROWS2 / 4, 256, 0, stream>>>(x_s, x_l, xn);
    fused_kernel<<<512, 512, 0, stream>>>(xn, WpF, WvuF, descF, b_proj, bvu, w_attn,
                                          xpraw, invn, Araw, out + 10);
    asoftmax_kernel<<<4, 256, 0, stream>>>(Araw, mg);
    pool_kernel<<<dim3(64, 4), 256, 0, stream>>>(Araw, invn, mg, xpraw, slideAll);
    finalize_kernel<<<1, 512, 0, stream>>>(slideAll, slideAll + 1024, desc, out);
}

// Round 9
// 362.528 us; speedup vs baseline: 1.0632x; 1.0632x over previous
//
#include <hip/hip_runtime.h>
#include <math.h>

#define B_ 2
#define N_ 16384
#define D_ 512
#define C_ 4
#define K_ 8
#define ROWS (B_*N_)      // 32768 rows per side
#define ROWS2 (2*ROWS)    // 65536 rows both sides
#define EPS_ 1e-12f

typedef unsigned short u16;
typedef unsigned int u32;
using short8  = __attribute__((ext_vector_type(8))) short;
using float4v = __attribute__((ext_vector_type(4))) float;

__device__ __forceinline__ u16 f2bf(float f) {
    union { float f; u32 u; } v; v.f = f;
    u32 r = v.u + 0x7fffu + ((v.u >> 16) & 1u);
    return (u16)(r >> 16);
}
__device__ __forceinline__ u32 pack2(float a, float b) {
    return (u32)f2bf(a) | ((u32)f2bf(b) << 16);
}
__device__ __forceinline__ float bf2f(u16 h) {
    union { u32 u; float f; } v; v.u = ((u32)h) << 16;
    return v.f;
}
__device__ __forceinline__ float fsigmoid(float x) { return 1.0f / (1.0f + __expf(-x)); }
__device__ __forceinline__ float ftanh(float x)    { return 1.0f - 2.0f / (__expf(2.0f * x) + 1.0f); }

__device__ __forceinline__ void load_lds16(const u16* g, u16* l) {
    __builtin_amdgcn_global_load_lds(
        (const __attribute__((address_space(1))) u32*)g,
        (__attribute__((address_space(3))) u32*)l, 16, 0, 0);
}
// Stage 8 rows x 64 k (bf16) of a row-major tile (row stride 512 u16) into LDS,
// fully coalesced, XOR-swizzled. LDS addr(r,c)=r*64 + (c^(r&7))*8 (u16).
__device__ __forceinline__ void stage_rows8(const u16* gtile, u16* ldsTile, int g, int lane) {
    int rg = lane >> 3;
    int c  = (lane & 7) ^ rg;
    load_lds16(gtile + (size_t)(g * 8 + rg) * 512 + c * 8, ldsTile + g * 512);
}
#define AFRAG(lds, R, c) (*(const short8*)&(lds)[(R) * 64 + (((c) ^ ((R) & 7)) * 8)])
// Fragment-packed B: frag(nf, ks)[lane][e] = Bt[nf*16 + (lane&15)][ks*32 + (lane>>4)*8 + e]
#define BFRAG(Bf, nf, ks, lane) (*(const short8*)&(Bf)[((size_t)((nf) * 16 + (ks)) << 9) + ((lane) << 3)])

// ---------------- P0: weight prep (fragment-major packing) ----------------
__global__ __launch_bounds__(256) void prep_weights_kernel(
    const float* __restrict__ Wp, const float* __restrict__ Wv, const float* __restrict__ Wu,
    const float* __restrict__ bv, const float* __restrict__ bu, const float* __restrict__ desc,
    u16* __restrict__ WpF, u16* __restrict__ WvuF, float* __restrict__ bvu,
    u16* __restrict__ descF)
{
    int idx = blockIdx.x * 256 + threadIdx.x;   // 0 .. 262143
    // fragment decode: idx = ((nf*16 + ks)*64 + l)*8 + e
    int e = idx & 7, l = (idx >> 3) & 63, ks = (idx >> 9) & 15, nf = idx >> 13;
    int k = ks * 32 + ((l >> 4) << 3) + e;
    int n = (nf << 4) + (l & 15);
    WpF[idx] = f2bf(Wp[(size_t)k * 512 + n]);
    int half = nf & 1, h = (nf >> 1) * 16 + (l & 15);
    WvuF[idx] = f2bf(half ? Wu[(size_t)k * 256 + h] : Wv[(size_t)k * 256 + h]);
    if (idx < 512) {
        int tl = idx >> 4, pr = tl >> 1, hf = tl & 1, hh = pr * 16 + (idx & 15);
        bvu[idx] = hf ? bu[hh] : bv[hh];
    }
    if (idx < 16384) {
        int j = idx & 7, dl = (idx >> 3) & 63, g = (idx >> 9) & 1, kt = idx >> 10;
        descF[idx] = f2bf(desc[(size_t)(g * 16 + (dl & 15)) * 512 + kt * 32 + (dl >> 4) * 8 + j]);
    }
}

// ---------------- K0: per-row L2-normalize x and cast to bf16 (both sides) ---------
__global__ __launch_bounds__(256) void rownorm_cast_kernel(
    const float* __restrict__ x_s, const float* __restrict__ x_l, u16* __restrict__ xn)
{
    int wave = threadIdx.x >> 6, lane = threadIdx.x & 63;
    size_t row = (size_t)blockIdx.x * 4 + wave;
    const float* xr = (row < (size_t)ROWS) ? (x_s + row * D_)
                                           : (x_l + (row - ROWS) * D_);
    float4 a = *(const float4*)&xr[lane * 8];
    float4 b = *(const float4*)&xr[lane * 8 + 4];
    float s = a.x*a.x + a.y*a.y + a.z*a.z + a.w*a.w
            + b.x*b.x + b.y*b.y + b.z*b.z + b.w*b.w;
#pragma unroll
    for (int off = 32; off; off >>= 1) s += __shfl_xor(s, off, 64);
    float inv = 1.0f / fmaxf(sqrtf(s), EPS_);
    uint4 o;
    o.x = pack2(a.x * inv, a.y * inv);
    o.y = pack2(a.z * inv, a.w * inv);
    o.z = pack2(b.x * inv, b.y * inv);
    o.w = pack2(b.z * inv, b.w * inv);
    *(uint4*)&xn[row * D_ + lane * 8] = o;
}

// ---------------- K1: FUSED proj-GEMM -> LDS tile -> gate-GEMM + cls + Gram -------
// 64-row M-tile, full N=512, 8 waves; 64 KB tile -> 2 blocks/CU (16 waves/CU).
// Loop 1: distance-2 chunk prefetch, counted vmcnt(1), B-frags loaded BEFORE stage
// so compiler B-waits never drain the in-flight stage.
__global__ __launch_bounds__(512, 2) void fused_kernel(
    const u16* __restrict__ A,          // xn
    const u16* __restrict__ BpF,        // W_proj frag-packed
    const u16* __restrict__ BvuF,       // Wv/Wu frag-packed interleaved
    const u16* __restrict__ descF,
    const float* __restrict__ bias,     // b_proj
    const float* __restrict__ bvu, const float* __restrict__ w_attn,
    u16* __restrict__ Cp,               // xpraw out (global, for pool)
    float* __restrict__ invn, float* __restrict__ Araw,
    float* __restrict__ out10)
{
    __shared__ u16 tile[32768];         // 64 KB: xn chunks during loop 1, xpraw tile after
    __shared__ float sInvF[64];
    __shared__ float redA[256];
    int t = threadIdx.x, wave = t >> 6, lane = t & 63;
    int lr = lane & 15, lq = lane >> 4;
    int wm = wave >> 2, wn = wave & 3;  // wave covers rows wm*32..+32, cols wn*128..+128
    const bool doCls = (wave < 4);
    int M0 = blockIdx.x * 64;
    const u16* Arow = A + (size_t)M0 * 512;

    // ================= loop 1: xpraw = xn @ Wp + b =================
    float4v acc1[2][8];
#pragma unroll
    for (int i = 0; i < 2; ++i)
#pragma unroll
        for (int j = 0; j < 8; ++j)
#pragma unroll
            for (int r = 0; r < 4; ++r) acc1[i][j][r] = 0.f;

    // chunk c = 64 rows x 64 k = 4096 u16; one stage op per wave (g = wave).
#define STAGE1(c) stage_rows8(Arow + (c) * 64, tile + (size_t)(c) * 4096, wave, lane)
#define GCOMP1(TCH, BR) \
    { _Pragma("unroll") \
      for (int kt = 0; kt < 2; ++kt) { \
          short8 af[2]; \
          _Pragma("unroll") \
          for (int i_ = 0; i_ < 2; ++i_) \
              af[i_] = AFRAG(TCH, wm * 32 + i_ * 16 + lr, kt * 4 + lq); \
          _Pragma("unroll") \
          for (int i_ = 0; i_ < 2; ++i_) \
              _Pragma("unroll") \
              for (int j_ = 0; j_ < 8; ++j_) \
                  acc1[i_][j_] = __builtin_amdgcn_mfma_f32_16x16x32_bf16(BR[kt * 8 + j_], af[i_], acc1[i_][j_], 0, 0, 0); \
      } }
#define LOADB1(BR, ttv) \
    { _Pragma("unroll") \
      for (int j_ = 0; j_ < 8; ++j_) { \
          BR[j_]     = BFRAG(BpF, wn * 8 + j_, (ttv) * 2 + 0, lane); \
          BR[8 + j_] = BFRAG(BpF, wn * 8 + j_, (ttv) * 2 + 1, lane); \
      } }

    STAGE1(0); STAGE1(1);
    asm volatile("s_waitcnt vmcnt(1)" ::: "memory");   // chunk 0 drained; chunk 1 in flight
    __builtin_amdgcn_s_barrier();

#pragma unroll 1
    for (int tt = 0; tt < 6; ++tt) {
        short8 bfr[16];
        LOADB1(bfr, tt);
        asm volatile("" ::: "memory");     // pin: B loads issue BEFORE next stage
        STAGE1(tt + 2);
        const u16* tch = tile + (size_t)tt * 4096;
        GCOMP1(tch, bfr);
        asm volatile("s_waitcnt vmcnt(1)" ::: "memory");   // chunk tt+1 drained; tt+2 in flight
        __builtin_amdgcn_s_barrier();
    }
    {   // tt = 6
        short8 bfr[16];
        LOADB1(bfr, 6);
        const u16* tch = tile + (size_t)6 * 4096;
        GCOMP1(tch, bfr);
        asm volatile("s_waitcnt vmcnt(0)" ::: "memory");   // chunk 7 ready
        __builtin_amdgcn_s_barrier();
    }
    {   // tt = 7
        short8 bfr[16];
        LOADB1(bfr, 7);
        const u16* tch = tile + (size_t)7 * 4096;
        GCOMP1(tch, bfr);
    }
    __syncthreads();   // all waves done reading xn chunks before epilogue overwrites tile

    // ---- epilogue 1: +bias, bf16-round, write global xpraw AND the LDS tile ----
    {
        float4 b4[8];
#pragma unroll
        for (int j = 0; j < 8; ++j)
            b4[j] = *(const float4*)&bias[wn * 128 + j * 16 + lq * 4];
#pragma unroll
        for (int i = 0; i < 2; ++i) {
            int row = wm * 32 + i * 16 + lr;
            u16* crow = Cp + (size_t)(M0 + row) * 512;
#pragma unroll
            for (int j = 0; j < 8; ++j) {
                int col = wn * 128 + j * 16 + lq * 4;
                u16 h0 = f2bf(acc1[i][j][0] + b4[j].x);
                u16 h1 = f2bf(acc1[i][j][1] + b4[j].y);
                u16 h2 = f2bf(acc1[i][j][2] + b4[j].z);
                u16 h3 = f2bf(acc1[i][j][3] + b4[j].w);
                uint2 o;
                o.x = (u32)h0 | ((u32)h1 << 16);
                o.y = (u32)h2 | ((u32)h3 << 16);
                *(uint2*)&crow[col] = o;
                // LDS tile write in the SAME swizzled layout AFRAG expects:
                int kc = col >> 6, cc = col & 63;
                int c8 = cc >> 3, off8 = cc & 7;   // off8 in {0,4}
                *(uint2*)&tile[kc * 4096 + row * 64 + ((c8 ^ (row & 7)) * 8) + off8] = o;
            }
        }
    }
    __syncthreads();   // tile fully visible; loop 2 below is barrier-free

    // ================= loop 2: gate GEMM + cls + Gram, A from LDS =================
    float4v acc2[2][8];
    float4v accS[2], accG;
#pragma unroll
    for (int i = 0; i < 2; ++i)
#pragma unroll
        for (int j = 0; j < 8; ++j)
#pragma unroll
            for (int r = 0; r < 4; ++r) acc2[i][j][r] = 0.f;
#pragma unroll
    for (int r = 0; r < 4; ++r) { accS[0][r] = 0.f; accS[1][r] = 0.f; accG[r] = 0.f; }

#pragma unroll 2
    for (int tt = 0; tt < 8; ++tt) {
        const u16* tch = tile + (size_t)tt * 4096;
#pragma unroll
        for (int kt = 0; kt < 2; ++kt) {
            int ks = tt * 2 + kt;
            // cls + Gram: waves 0-3 cover the 64 rows (16 each)
            if (doCls) {
                short8 afc = AFRAG(tch, wave * 16 + lr, kt * 4 + lq);
                short8 d0 = *(const short8*)&descF[((ks * 2 + 0) << 9) + (lane << 3)];
                short8 d1 = *(const short8*)&descF[((ks * 2 + 1) << 9) + (lane << 3)];
                accS[0] = __builtin_amdgcn_mfma_f32_16x16x32_bf16(afc, d0, accS[0], 0, 0, 0);
                accS[1] = __builtin_amdgcn_mfma_f32_16x16x32_bf16(afc, d1, accS[1], 0, 0, 0);
                accG    = __builtin_amdgcn_mfma_f32_16x16x32_bf16(afc, afc, accG, 0, 0, 0);
            }
            // main gate GEMM
            short8 af[2], bfr[8];
#pragma unroll
            for (int i = 0; i < 2; ++i)
                af[i] = AFRAG(tch, wm * 32 + i * 16 + lr, kt * 4 + lq);
#pragma unroll
            for (int j = 0; j < 8; ++j)
                bfr[j] = BFRAG(BvuF, wn * 8 + j, ks, lane);
#pragma unroll
            for (int i = 0; i < 2; ++i)
#pragma unroll
                for (int j = 0; j < 8; ++j)
                    acc2[i][j] = __builtin_amdgcn_mfma_f32_16x16x32_bf16(bfr[j], af[i], acc2[i][j], 0, 0, 0);
        }
    }

    // ---- invn from Gram diagonal (waves 0-3, rows wave*16..+16) ----
    if (doCls) {
#pragma unroll
        for (int r = 0; r < 4; ++r) {
            if (lr == lq * 4 + r) {
                float iv = 1.0f / fmaxf(sqrtf(accG[r]), EPS_);
                sInvF[wave * 16 + lq * 4 + r] = iv;
                invn[M0 + wave * 16 + lq * 4 + r] = iv;
            }
        }
    }
    __syncthreads();

    // ---- class scores (waves 0-3) ----
    if (doCls) {
        const float scale = 0.04419417382415922f;   // 512^-0.5
        int side = (M0 >= ROWS) ? 1 : 0;
        float* cls = out10 + (size_t)side * ((size_t)ROWS * 4);
        int rbase = M0 - side * ROWS + wave * 16;
#pragma unroll
        for (int r = 0; r < 4; ++r) {
            int rloc = rbase + lq * 4 + r;
            float iv = sInvF[wave * 16 + lq * 4 + r];
            float sv0 = accS[0][r] * iv, sv1 = accS[1][r] * iv;
#pragma unroll
            for (int g = 0; g < 2; ++g) {
                float s = g ? sv1 : sv0;
                float ts = s * scale;
                float mx = ts;
                mx = fmaxf(mx, __shfl_xor(mx, 1, 64));
                mx = fmaxf(mx, __shfl_xor(mx, 2, 64));
                mx = fmaxf(mx, __shfl_xor(mx, 4, 64));
                float e = __expf(ts - mx);
                float num = e * s, den = e;
                num += __shfl_xor(num, 1, 64); den += __shfl_xor(den, 1, 64);
                num += __shfl_xor(num, 2, 64); den += __shfl_xor(den, 2, 64);
                num += __shfl_xor(num, 4, 64); den += __shfl_xor(den, 4, 64);
                if ((lr & 7) == 0) {
                    int c = g * 2 + ((lr >> 3) & 1);
                    cls[(size_t)rloc * 4 + c] = num / den;
                }
            }
        }
    }

    // ---- gated-attention scalar: full row in block -> single Araw ----
    {
        int colbase = wn * 128;
        int hbase = wn * 64;
        float4 bv4[4], bu4[4], w4[4];
#pragma unroll
        for (int p = 0; p < 4; ++p) {
            int nv = colbase + p * 32 + lq * 4;
            bv4[p] = *(const float4*)&bvu[nv];
            bu4[p] = *(const float4*)&bvu[nv + 16];
            w4[p]  = *(const float4*)&w_attn[hbase + p * 16 + lq * 4];
        }
#pragma unroll
        for (int i = 0; i < 2; ++i) {
            int rloc = wm * 32 + i * 16 + lr;
            float iv = sInvF[rloc];
            float part = 0.f;
#pragma unroll
            for (int p = 0; p < 4; ++p) {
#pragma unroll
                for (int r = 0; r < 4; ++r) {
                    float v = acc2[i][2 * p][r] * iv + (&bv4[p].x)[r];
                    float u = acc2[i][2 * p + 1][r] * iv + (&bu4[p].x)[r];
                    part += ftanh(v) * (&w4[p].x)[r] * fsigmoid(u);
                }
            }
            part += __shfl_xor(part, 16, 64);
            part += __shfl_xor(part, 32, 64);
            if (lq == 0) redA[wn * 64 + rloc] = part;
        }
    }
    __syncthreads();
    if (t < 64)
        Araw[M0 + t] = redA[t] + redA[64 + t] + redA[128 + t] + redA[192 + t];
}

// ---------------- K5: per-group softmax stats (max, 1/expsum) in one kernel -------
// grid (4): one block per (side,batch) group of 16384 rows.
__global__ __launch_bounds__(256) void asoftmax_kernel(
    const float* __restrict__ Araw, float* __restrict__ mg)
{
    __shared__ float red[256];
    int t = threadIdx.x, g = blockIdx.x;
    const float4* a4 = (const float4*)(Araw + (size_t)g * N_);
    float m = -1e30f;
    for (int i = t; i < N_ / 4; i += 256) {
        float4 v = a4[i];
        m = fmaxf(m, fmaxf(fmaxf(v.x, v.y), fmaxf(v.z, v.w)));
    }
    red[t] = m; __syncthreads();
    for (int s = 128; s; s >>= 1) { if (t < s) red[t] = fmaxf(red[t], red[t + s]); __syncthreads(); }
    m = red[0]; __syncthreads();
    float e = 0.f;
    for (int i = t; i < N_ / 4; i += 256) {
        float4 v = a4[i];
        e += __expf(v.x - m) + __expf(v.y - m) + __expf(v.z - m) + __expf(v.w - m);
    }
    red[t] = e; __syncthreads();
    for (int s = 128; s; s >>= 1) { if (t < s) red[t] += red[t + s]; __syncthreads(); }
    if (t == 0) {
        mg[g * 2] = m;
        mg[g * 2 + 1] = 1.0f / red[0];
    }
}

// ---------------- K6: pooling with inline softmax normalize ----------------
__global__ __launch_bounds__(256) void pool_kernel(
    const float* __restrict__ Araw, const float* __restrict__ invn,
    const float* __restrict__ mg, const u16* __restrict__ xpraw,
    float* __restrict__ slideAll)
{
    __shared__ float lds[4][512];
    int t = threadIdx.x, wave = t >> 6, lane = t & 63;
    int g = blockIdx.y;
    float m = mg[g * 2], is = mg[g * 2 + 1];
    size_t row0 = (size_t)g * N_ + (size_t)blockIdx.x * 256 + wave;
    float a[8] = {};
    for (int r = 0; r < 64; ++r) {
        size_t row = row0 + r * 4;
        float av = __expf(Araw[row] - m) * is * invn[row];
        uint4 pk = *(const uint4*)&xpraw[row * D_ + lane * 8];
        a[0] += av * bf2f((u16)pk.x); a[1] += av * bf2f((u16)(pk.x >> 16));
        a[2] += av * bf2f((u16)pk.y); a[3] += av * bf2f((u16)(pk.y >> 16));
        a[4] += av * bf2f((u16)pk.z); a[5] += av * bf2f((u16)(pk.z >> 16));
        a[6] += av * bf2f((u16)pk.w); a[7] += av * bf2f((u16)(pk.w >> 16));
    }
#pragma unroll
    for (int i = 0; i < 8; ++i) lds[wave][lane * 8 + i] = a[i];
    __syncthreads();
#pragma unroll
    for (int q = 0; q < 2; ++q) {
        int c = t * 2 + q;
        float s = lds[0][c] + lds[1][c] + lds[2][c] + lds[3][c];
        atomicAdd(&slideAll[(size_t)g * 512 + c], s);
    }
}

// ---------------- K7: finalize ----------------
__global__ __launch_bounds__(512) void finalize_kernel(
    const float* __restrict__ slide_s, const float* __restrict__ slide_l,
    const float* __restrict__ desc, float* __restrict__ out)
{
    __shared__ float txt[4][512];
    __shared__ float ssn[2][512];
    __shared__ float sln[2][512];
    __shared__ float red[512];
    __shared__ float lg[8];
    int t = threadIdx.x;

    auto reduceSum = [&](float v) -> float {
        red[t] = v; __syncthreads();
        for (int s = 256; s; s >>= 1) { if (t < s) red[t] += red[t + s]; __syncthreads(); }
        float r = red[0]; __syncthreads();
        return r;
    };

    for (int c = 0; c < 4; ++c) {
        float m = -1e30f;
        for (int k = 0; k < 8; ++k) m = fmaxf(m, desc[((size_t)c * 8 + k) * 512 + t]);
        float ss = reduceSum(m * m);
        txt[c][t] = m / fmaxf(sqrtf(ss), EPS_);
    }
    for (int b = 0; b < 2; ++b) {
        float v = slide_s[b * 512 + t];
        float ss = reduceSum(v * v);
        ssn[b][t] = v / fmaxf(sqrtf(ss), EPS_);
        v = slide_l[b * 512 + t];
        ss = reduceSum(v * v);
        sln[b][t] = v / fmaxf(sqrtf(ss), EPS_);
    }
    __syncthreads();
    for (int b = 0; b < 2; ++b)
        for (int c = 0; c < 4; ++c) {
            float v = ssn[b][t] * txt[c][t] + sln[b][t] * txt[c][t];
            float s = reduceSum(v);
            if (t == 0) lg[b * 4 + c] = s;
        }
    __syncthreads();
    if (t < 2) {
        int b = t;
        float m = -1e30f;
        for (int c = 0; c < 4; ++c) m = fmaxf(m, lg[b * 4 + c]);
        float e[4]; float den = 0.f;
        for (int c = 0; c < 4; ++c) { e[c] = expf(lg[b * 4 + c] - m); den += e[c]; }
        int am = 0; float bm = -1.f;
        for (int c = 0; c < 4; ++c) {
            float pcl = e[c] / den;
            out[b * 4 + c] = pcl;
            if (pcl > bm) { bm = pcl; am = c; }
        }
        out[8 + b] = (float)am;
    }
}

extern "C" void kernel_launch(void* const* d_in, const int* in_sizes, int n_in,
                              void* d_out, int out_size, void* d_ws, size_t ws_size,
                              hipStream_t stream) {
    const float* x_s    = (const float*)d_in[0];
    const float* x_l    = (const float*)d_in[2];
    const float* W_proj = (const float*)d_in[4];
    const float* b_proj = (const float*)d_in[5];
    const float* desc   = (const float*)d_in[6];
    const float* Wv     = (const float*)d_in[7];
    const float* bv     = (const float*)d_in[8];
    const float* Wu     = (const float*)d_in[9];
    const float* bu     = (const float*)d_in[10];
    const float* w_attn = (const float*)d_in[11];
    float* out = (float*)d_out;

    // workspace layout (bytes):
    //  0         : xn    bf16 [65536x512]  (67108864)
    //  67108864  : xpraw bf16 [65536x512]  (67108864)
    //  134217728 : WpF   bf16 frag-packed  (524288)
    //  134742016 : WvuF  bf16 frag-packed  (524288)
    //  135266304 : descF bf16 fragment     (32768)
    //  135299072 : bvu   f32 [512]         (2048)
    //  135301120 : invn  f32 [65536]       (262144)
    //  135563264 : Araw  f32 [65536]       (262144)
    //  135825408 : mg    f32 [4x2]         (1024 pad)
    //  135826432 : slideAll f32 [4x512]    (8192)
    char* w = (char*)d_ws;
    u16* xn        = (u16*)w;
    u16* xpraw     = (u16*)(w + 67108864);
    u16* WpF       = (u16*)(w + 134217728);
    u16* WvuF      = (u16*)(w + 134742016);
    u16* descF     = (u16*)(w + 135266304);
    float* bvu     = (float*)(w + 135299072);
    float* invn    = (float*)(w + 135301120);
    float* Araw    = (float*)(w + 135563264);
    float* mg      = (float*)(w + 135825408);
    float* slideAll= (float*)(w + 135826432);

    hipMemsetAsync(slideAll, 0, 8192, stream);
    prep_weights_kernel<<<1024, 256, 0, stream>>>(W_proj, Wv, Wu, bv, bu, desc,
                                                  WpF, WvuF, bvu, descF);

    rownorm_cast_kernel<<<ROWS2 / 4, 256, 0, stream>>>(x_s, x_l, xn);
    fused_kernel<<<1024, 512, 0, stream>>>(xn, WpF, WvuF, descF, b_proj, bvu, w_attn,
                                           xpraw, invn, Araw, out + 10);
    asoftmax_kernel<<<4, 256, 0, stream>>>(Araw, mg);
    pool_kernel<<<dim3(64, 4), 256, 0, stream>>>(Araw, invn, mg, xpraw, slideAll);
    finalize_kernel<<<1, 512, 0, stream>>>(slideAll, slideAll + 1024, desc, out);
}